// Round 1
// baseline (643.043 us; speedup 1.0000x reference)
//
#include <hip/hip_runtime.h>
#include <math.h>

// ---------------------------------------------------------------------------
// GCN 3-layer forward: h=x@W ; out = D^-1/2 (A+I) D^-1/2 h + b ; relu between
// layers; log_softmax on final pre-relu activations.
// ---------------------------------------------------------------------------

static inline size_t ws_align(size_t x) { return (x + 255) & ~size_t(255); }

__global__ void deg_kernel(const int* __restrict__ dst, int E, int* __restrict__ deg) {
    int e = blockIdx.x * blockDim.x + threadIdx.x;
    if (e < E) atomicAdd(&deg[dst[e]], 1);
}

__global__ void dinv_kernel(const int* __restrict__ deg, float* __restrict__ dinv, int n) {
    int i = blockIdx.x * blockDim.x + threadIdx.x;
    if (i < n) dinv[i] = rsqrtf((float)(deg[i] + 1));  // +1 self-loop
}

// out[row][j] = sum_k relu?(in[row][k]) * W[k][j]
// block: (64, 4) -> 4 rows per block; W staged in LDS.
template <int FIN, int FOUT, bool RELU_IN>
__global__ void gemm_kernel(const float* __restrict__ in, const float* __restrict__ W,
                            float* __restrict__ out, int n) {
    __shared__ float Ws[FIN * FOUT];
    __shared__ float rows[4][FIN];
    int tid = threadIdx.y * 64 + threadIdx.x;
    for (int i = tid; i < FIN * FOUT; i += 256) Ws[i] = W[i];
    int row = blockIdx.x * 4 + threadIdx.y;
    if (row < n) {
        float v = in[row * FIN + threadIdx.x];
        if (RELU_IN) v = fmaxf(v, 0.0f);
        rows[threadIdx.y][threadIdx.x] = v;
    }
    __syncthreads();
    if (row < n && threadIdx.x < FOUT) {
        float acc = 0.0f;
#pragma unroll
        for (int k = 0; k < FIN; ++k)
            acc = fmaf(rows[threadIdx.y][k], Ws[k * FOUT + threadIdx.x], acc);
        out[row * FOUT + threadIdx.x] = acc;
    }
}

// a[i][f] = h[i][f] * dinv[i]^2 + b[f]   (self-loop contribution + bias)
template <int F>
__global__ void agg_init_kernel(const float* __restrict__ h, const float* __restrict__ dinv,
                                const float* __restrict__ b, float* __restrict__ a, int n) {
    long long idx = (long long)blockIdx.x * blockDim.x + threadIdx.x;
    long long total = (long long)n * F;
    if (idx < total) {
        int i = (int)(idx / F);
        int f = (int)(idx - (long long)i * F);
        float di = dinv[i];
        a[idx] = h[idx] * di * di + b[f];
    }
}

// one 64-lane wave per edge: a[dst] += h[src] * dinv[src]*dinv[dst]
template <int F>
__global__ void edge_scatter_kernel(const int* __restrict__ src, const int* __restrict__ dst,
                                    const float* __restrict__ dinv, const float* __restrict__ h,
                                    float* __restrict__ a, int E) {
    int g = blockIdx.x * (blockDim.x >> 6) + (threadIdx.x >> 6);
    int f = threadIdx.x & 63;
    if (g >= E) return;
    int s = src[g], d = dst[g];
    float norm = dinv[s] * dinv[d];
    if (f < F) atomicAdd(&a[(long long)d * F + f], h[(long long)s * F + f] * norm);
}

// in-place log_softmax over C columns; one wave per row
template <int C>
__global__ void logsoftmax_kernel(float* __restrict__ out, int n) {
    int wave = threadIdx.x >> 6;
    int lane = threadIdx.x & 63;
    int row = blockIdx.x * 4 + wave;
    if (row >= n) return;
    float v = (lane < C) ? out[(long long)row * C + lane] : -INFINITY;
    float m = v;
#pragma unroll
    for (int off = 32; off >= 1; off >>= 1) m = fmaxf(m, __shfl_xor(m, off, 64));
    float e = (lane < C) ? expf(v - m) : 0.0f;
    float s = e;
#pragma unroll
    for (int off = 32; off >= 1; off >>= 1) s += __shfl_xor(s, off, 64);
    if (lane < C) out[(long long)row * C + lane] = v - m - logf(s);
}

extern "C" void kernel_launch(void* const* d_in, const int* in_sizes, int n_in,
                              void* d_out, int out_size, void* d_ws, size_t ws_size,
                              hipStream_t stream) {
    const float* x  = (const float*)d_in[0];
    const int*   ei = (const int*)d_in[1];
    const float* W0 = (const float*)d_in[2];
    const float* b0 = (const float*)d_in[3];
    const float* W1 = (const float*)d_in[4];
    const float* b1 = (const float*)d_in[5];
    const float* W2 = (const float*)d_in[6];
    const float* b2 = (const float*)d_in[7];
    float* out = (float*)d_out;

    const int H   = in_sizes[3];            // 64
    const int FIN = in_sizes[2] / H;        // 64
    const int n   = in_sizes[0] / FIN;      // 50000
    const int C   = in_sizes[7];            // 40
    const int E   = in_sizes[1] / 2;        // 800000
    (void)C; (void)FIN;

    const int* srcp = ei;
    const int* dstp = ei + E;

    char* ws = (char*)d_ws;
    size_t off = 0;
    float* dinv = (float*)(ws + off); off += ws_align((size_t)n * 4);
    int*   deg  = (int*)(ws + off);   off += ws_align((size_t)n * 4);
    float* buf0 = (float*)(ws + off); off += ws_align((size_t)n * H * 4);
    float* buf1 = (float*)(ws + off); off += ws_align((size_t)n * H * 4);

    // degrees + dinv (must re-zero every call: atomics accumulate)
    hipMemsetAsync(deg, 0, (size_t)n * 4, stream);
    deg_kernel<<<(E + 255) / 256, 256, 0, stream>>>(dstp, E, deg);
    dinv_kernel<<<(n + 255) / 256, 256, 0, stream>>>(deg, dinv, n);

    dim3 gblk(64, 4);
    int gemm_grid = (n + 3) / 4;
    int edge_grid = (E + 3) / 4;

    // layer 0: x @ W0 -> buf0 ; agg -> buf1
    gemm_kernel<64, 64, false><<<gemm_grid, gblk, 0, stream>>>(x, W0, buf0, n);
    agg_init_kernel<64><<<((long long)n * 64 + 255) / 256, 256, 0, stream>>>(buf0, dinv, b0, buf1, n);
    edge_scatter_kernel<64><<<edge_grid, 256, 0, stream>>>(srcp, dstp, dinv, buf0, buf1, E);

    // layer 1: relu(buf1) @ W1 -> buf0 ; agg -> buf1
    gemm_kernel<64, 64, true><<<gemm_grid, gblk, 0, stream>>>(buf1, W1, buf0, n);
    agg_init_kernel<64><<<((long long)n * 64 + 255) / 256, 256, 0, stream>>>(buf0, dinv, b1, buf1, n);
    edge_scatter_kernel<64><<<edge_grid, 256, 0, stream>>>(srcp, dstp, dinv, buf0, buf1, E);

    // layer 2: relu(buf1) @ W2 -> buf0 (n x 40) ; agg -> out ; log_softmax
    gemm_kernel<64, 40, true><<<gemm_grid, gblk, 0, stream>>>(buf1, W2, buf0, n);
    agg_init_kernel<40><<<((long long)n * 40 + 255) / 256, 256, 0, stream>>>(buf0, dinv, b2, out, n);
    edge_scatter_kernel<40><<<edge_grid, 256, 0, stream>>>(srcp, dstp, dinv, buf0, out, E);
    logsoftmax_kernel<40><<<(n + 3) / 4, 256, 0, stream>>>(out, n);
}

// Round 2
// 351.367 us; speedup vs baseline: 1.8301x; 1.8301x over previous
//
#include <hip/hip_runtime.h>
#include <math.h>

static inline size_t ws_align(size_t x) { return (x + 255) & ~size_t(255); }

// ---------------- degree histogram + dinv ----------------
__global__ void deg_kernel(const int* __restrict__ dst, int E, int* __restrict__ deg) {
    int e = blockIdx.x * blockDim.x + threadIdx.x;
    if (e < E) atomicAdd(&deg[dst[e]], 1);
}

__global__ void dinv_kernel(const int* __restrict__ deg, float* __restrict__ dinv, int n) {
    int i = blockIdx.x * blockDim.x + threadIdx.x;
    if (i < n) dinv[i] = rsqrtf((float)(deg[i] + 1));  // +1 self-loop
}

// ---------------- exclusive scan of deg -> rowptr (1024 elems/block) ----------
__global__ void scan1_kernel(const int* __restrict__ deg, int* __restrict__ bsum, int n) {
    __shared__ int sdata[256];
    int base = blockIdx.x * 1024;
    int sum = 0;
    for (int i = threadIdx.x; i < 1024; i += 256) {
        int idx = base + i;
        if (idx < n) sum += deg[idx];
    }
    sdata[threadIdx.x] = sum;
    __syncthreads();
    for (int s = 128; s > 0; s >>= 1) {
        if (threadIdx.x < s) sdata[threadIdx.x] += sdata[threadIdx.x + s];
        __syncthreads();
    }
    if (threadIdx.x == 0) bsum[blockIdx.x] = sdata[0];
}

__global__ void scan2_kernel(int* __restrict__ bsum, int nb) {  // nb <= 256, 1 block
    __shared__ int sdata[256];
    int v = (threadIdx.x < nb) ? bsum[threadIdx.x] : 0;
    sdata[threadIdx.x] = v;
    __syncthreads();
    for (int off = 1; off < 256; off <<= 1) {
        int t = (threadIdx.x >= off) ? sdata[threadIdx.x - off] : 0;
        __syncthreads();
        sdata[threadIdx.x] += t;
        __syncthreads();
    }
    if (threadIdx.x < nb) bsum[threadIdx.x] = sdata[threadIdx.x] - v;  // exclusive
}

__global__ void scan3_kernel(const int* __restrict__ deg, const int* __restrict__ bsum,
                             int* __restrict__ rowptr, int n) {
    __shared__ int ssum[256];
    int base = blockIdx.x * 1024 + threadIdx.x * 4;
    int v[4];
    int s = 0;
#pragma unroll
    for (int k = 0; k < 4; ++k) {
        int idx = base + k;
        v[k] = (idx < n) ? deg[idx] : 0;
        s += v[k];
    }
    ssum[threadIdx.x] = s;
    __syncthreads();
    for (int off = 1; off < 256; off <<= 1) {
        int t = (threadIdx.x >= off) ? ssum[threadIdx.x - off] : 0;
        __syncthreads();
        ssum[threadIdx.x] += t;
        __syncthreads();
    }
    int ex = (threadIdx.x > 0 ? ssum[threadIdx.x - 1] : 0) + bsum[blockIdx.x];
#pragma unroll
    for (int k = 0; k < 4; ++k) {
        int idx = base + k;
        if (idx < n) rowptr[idx] = ex;
        ex += v[k];
    }
}

// ---------------- CSR fill: adj[pos]=src, wgt[pos]=dinv[s]*dinv[d] -----------
__global__ void fill_kernel(const int* __restrict__ src, const int* __restrict__ dst,
                            const float* __restrict__ dinv, const int* __restrict__ rowptr,
                            int* __restrict__ cursor, int* __restrict__ adj,
                            float* __restrict__ wgt, int E) {
    int e = blockIdx.x * blockDim.x + threadIdx.x;
    if (e >= E) return;
    int s = src[e], d = dst[e];
    int pos = rowptr[d] + atomicAdd(&cursor[d], 1);
    adj[pos] = s;
    wgt[pos] = dinv[s] * dinv[d];
}

// ---------------- dense transform (unchanged) --------------------------------
template <int FIN, int FOUT, bool RELU_IN>
__global__ void gemm_kernel(const float* __restrict__ in, const float* __restrict__ W,
                            float* __restrict__ out, int n) {
    __shared__ float Ws[FIN * FOUT];
    __shared__ float rows[4][FIN];
    int tid = threadIdx.y * 64 + threadIdx.x;
    for (int i = tid; i < FIN * FOUT; i += 256) Ws[i] = W[i];
    int row = blockIdx.x * 4 + threadIdx.y;
    if (row < n) {
        float v = in[row * FIN + threadIdx.x];
        if (RELU_IN) v = fmaxf(v, 0.0f);
        rows[threadIdx.y][threadIdx.x] = v;
    }
    __syncthreads();
    if (row < n && threadIdx.x < FOUT) {
        float acc = 0.0f;
#pragma unroll
        for (int k = 0; k < FIN; ++k)
            acc = fmaf(rows[threadIdx.y][k], Ws[k * FOUT + threadIdx.x], acc);
        out[row * FOUT + threadIdx.x] = acc;
    }
}

// ---------------- gather-aggregate: one wave per node, lane = feature --------
// out[i] = h[i]*dinv[i]^2 + b + sum_{e: dst=i} h[src_e] * wgt_e
template <int F>
__global__ void gather_kernel(const int* __restrict__ rowptr, const int* __restrict__ deg,
                              const int* __restrict__ adj, const float* __restrict__ wgt,
                              const float* __restrict__ h, const float* __restrict__ dinv,
                              const float* __restrict__ b, float* __restrict__ out, int n) {
    int node = blockIdx.x * 4 + (threadIdx.x >> 6);
    int lane = threadIdx.x & 63;
    if (node >= n) return;
    float di = dinv[node];
    float acc = 0.0f;
    if (lane < F) acc = h[(long long)node * F + lane] * di * di + b[lane];
    int r0 = rowptr[node];
    int cnt = deg[node];
    for (int j0 = 0; j0 < cnt; j0 += 64) {
        int m = min(64, cnt - j0);
        int s = 0;
        float w = 0.0f;
        if (lane < m) {
            s = adj[r0 + j0 + lane];   // coalesced
            w = wgt[r0 + j0 + lane];
        }
        for (int t = 0; t < m; ++t) {
            int st = __shfl(s, t, 64);
            float wt = __shfl(w, t, 64);
            if (lane < F) acc = fmaf(h[(long long)st * F + lane], wt, acc);
        }
    }
    if (lane < F) out[(long long)node * F + lane] = acc;
}

// ---------------- log_softmax over C cols, one wave per row ------------------
template <int C>
__global__ void logsoftmax_kernel(float* __restrict__ out, int n) {
    int wave = threadIdx.x >> 6;
    int lane = threadIdx.x & 63;
    int row = blockIdx.x * 4 + wave;
    if (row >= n) return;
    float v = (lane < C) ? out[(long long)row * C + lane] : -INFINITY;
    float m = v;
#pragma unroll
    for (int off = 32; off >= 1; off >>= 1) m = fmaxf(m, __shfl_xor(m, off, 64));
    float e = (lane < C) ? expf(v - m) : 0.0f;
    float s = e;
#pragma unroll
    for (int off = 32; off >= 1; off >>= 1) s += __shfl_xor(s, off, 64);
    if (lane < C) out[(long long)row * C + lane] = v - m - logf(s);
}

extern "C" void kernel_launch(void* const* d_in, const int* in_sizes, int n_in,
                              void* d_out, int out_size, void* d_ws, size_t ws_size,
                              hipStream_t stream) {
    const float* x  = (const float*)d_in[0];
    const int*   ei = (const int*)d_in[1];
    const float* W0 = (const float*)d_in[2];
    const float* b0 = (const float*)d_in[3];
    const float* W1 = (const float*)d_in[4];
    const float* b1 = (const float*)d_in[5];
    const float* W2 = (const float*)d_in[6];
    const float* b2 = (const float*)d_in[7];
    float* out = (float*)d_out;

    const int H   = in_sizes[3];            // 64
    const int FIN = in_sizes[2] / H;        // 64
    const int n   = in_sizes[0] / FIN;      // 50000
    const int E   = in_sizes[1] / 2;        // 800000
    (void)FIN;

    const int* srcp = ei;
    const int* dstp = ei + E;

    char* ws = (char*)d_ws;
    size_t off = 0;
    int*   deg    = (int*)(ws + off);   off += ws_align((size_t)n * 4);
    int*   cursor = (int*)(ws + off);   off += ws_align((size_t)n * 4);
    int*   rowptr = (int*)(ws + off);   off += ws_align((size_t)n * 4);
    int*   bsum   = (int*)(ws + off);   off += ws_align(256 * 4);
    float* dinv   = (float*)(ws + off); off += ws_align((size_t)n * 4);
    int*   adj    = (int*)(ws + off);   off += ws_align((size_t)E * 4);
    float* wgt    = (float*)(ws + off); off += ws_align((size_t)E * 4);
    float* buf0   = (float*)(ws + off); off += ws_align((size_t)n * H * 4);
    float* buf1   = (float*)(ws + off); off += ws_align((size_t)n * H * 4);

    // zero deg + cursor (adjacent -> single memset covers both)
    hipMemsetAsync(deg, 0, ws_align((size_t)n * 4) * 2, stream);

    // CSR build
    deg_kernel<<<(E + 255) / 256, 256, 0, stream>>>(dstp, E, deg);
    dinv_kernel<<<(n + 255) / 256, 256, 0, stream>>>(deg, dinv, n);
    int nscan = (n + 1023) / 1024;  // 49
    scan1_kernel<<<nscan, 256, 0, stream>>>(deg, bsum, n);
    scan2_kernel<<<1, 256, 0, stream>>>(bsum, nscan);
    scan3_kernel<<<nscan, 256, 0, stream>>>(deg, bsum, rowptr, n);
    fill_kernel<<<(E + 255) / 256, 256, 0, stream>>>(srcp, dstp, dinv, rowptr, cursor, adj, wgt, E);

    dim3 gblk(64, 4);
    int gemm_grid = (n + 3) / 4;
    int node_grid = (n + 3) / 4;

    // layer 0
    gemm_kernel<64, 64, false><<<gemm_grid, gblk, 0, stream>>>(x, W0, buf0, n);
    gather_kernel<64><<<node_grid, 256, 0, stream>>>(rowptr, deg, adj, wgt, buf0, dinv, b0, buf1, n);
    // layer 1
    gemm_kernel<64, 64, true><<<gemm_grid, gblk, 0, stream>>>(buf1, W1, buf0, n);
    gather_kernel<64><<<node_grid, 256, 0, stream>>>(rowptr, deg, adj, wgt, buf0, dinv, b1, buf1, n);
    // layer 2
    gemm_kernel<64, 40, true><<<gemm_grid, gblk, 0, stream>>>(buf1, W2, buf0, n);
    gather_kernel<40><<<node_grid, 256, 0, stream>>>(rowptr, deg, adj, wgt, buf0, dinv, b2, out, n);
    logsoftmax_kernel<40><<<(n + 3) / 4, 256, 0, stream>>>(out, n);
}

// Round 3
// 277.912 us; speedup vs baseline: 2.3138x; 1.2643x over previous
//
#include <hip/hip_runtime.h>
#include <math.h>

static inline size_t ws_align(size_t x) { return (x + 255) & ~size_t(255); }

// ---------------- degree histogram + dinv ----------------
__global__ void deg_kernel(const int* __restrict__ dst, int E, int* __restrict__ deg) {
    int e = blockIdx.x * blockDim.x + threadIdx.x;
    if (e < E) atomicAdd(&deg[dst[e]], 1);
}

__global__ void dinv_kernel(const int* __restrict__ deg, float* __restrict__ dinv, int n) {
    int i = blockIdx.x * blockDim.x + threadIdx.x;
    if (i < n) dinv[i] = rsqrtf((float)(deg[i] + 1));  // +1 self-loop
}

// ---------------- exclusive scan of deg -> rowptr (1024 elems/block) ----------
__global__ void scan1_kernel(const int* __restrict__ deg, int* __restrict__ bsum, int n) {
    __shared__ int sdata[256];
    int base = blockIdx.x * 1024;
    int sum = 0;
    for (int i = threadIdx.x; i < 1024; i += 256) {
        int idx = base + i;
        if (idx < n) sum += deg[idx];
    }
    sdata[threadIdx.x] = sum;
    __syncthreads();
    for (int s = 128; s > 0; s >>= 1) {
        if (threadIdx.x < s) sdata[threadIdx.x] += sdata[threadIdx.x + s];
        __syncthreads();
    }
    if (threadIdx.x == 0) bsum[blockIdx.x] = sdata[0];
}

__global__ void scan2_kernel(int* __restrict__ bsum, int nb) {  // nb <= 256, 1 block
    __shared__ int sdata[256];
    int v = (threadIdx.x < nb) ? bsum[threadIdx.x] : 0;
    sdata[threadIdx.x] = v;
    __syncthreads();
    for (int off = 1; off < 256; off <<= 1) {
        int t = (threadIdx.x >= off) ? sdata[threadIdx.x - off] : 0;
        __syncthreads();
        sdata[threadIdx.x] += t;
        __syncthreads();
    }
    if (threadIdx.x < nb) bsum[threadIdx.x] = sdata[threadIdx.x] - v;  // exclusive
}

__global__ void scan3_kernel(const int* __restrict__ deg, const int* __restrict__ bsum,
                             int* __restrict__ rowptr, int n) {
    __shared__ int ssum[256];
    int base = blockIdx.x * 1024 + threadIdx.x * 4;
    int v[4];
    int s = 0;
#pragma unroll
    for (int k = 0; k < 4; ++k) {
        int idx = base + k;
        v[k] = (idx < n) ? deg[idx] : 0;
        s += v[k];
    }
    ssum[threadIdx.x] = s;
    __syncthreads();
    for (int off = 1; off < 256; off <<= 1) {
        int t = (threadIdx.x >= off) ? ssum[threadIdx.x - off] : 0;
        __syncthreads();
        ssum[threadIdx.x] += t;
        __syncthreads();
    }
    int ex = (threadIdx.x > 0 ? ssum[threadIdx.x - 1] : 0) + bsum[blockIdx.x];
#pragma unroll
    for (int k = 0; k < 4; ++k) {
        int idx = base + k;
        if (idx < n) rowptr[idx] = ex;
        ex += v[k];
    }
}

// ---------------- CSR fill: adj[pos]=src, wgt[pos]=dinv[s]*dinv[d] -----------
__global__ void fill_kernel(const int* __restrict__ src, const int* __restrict__ dst,
                            const float* __restrict__ dinv, const int* __restrict__ rowptr,
                            int* __restrict__ cursor, int* __restrict__ adj,
                            float* __restrict__ wgt, int E) {
    int e = blockIdx.x * blockDim.x + threadIdx.x;
    if (e >= E) return;
    int s = src[e], d = dst[e];
    int pos = rowptr[d] + atomicAdd(&cursor[d], 1);
    adj[pos] = s;
    wgt[pos] = dinv[s] * dinv[d];
}

// ---------------- dense transform: 4 waves x 8 row-iters per block -----------
template <int FIN, int FOUT, bool RELU_IN, int RLOOP>
__global__ void gemm_kernel(const float* __restrict__ in, const float* __restrict__ W,
                            float* __restrict__ out, int n) {
    __shared__ float Ws[FIN * FOUT];
    __shared__ float rowbuf[4][FIN];
    int lane = threadIdx.x & 63;
    int ty = threadIdx.x >> 6;
    for (int i = threadIdx.x; i < FIN * FOUT; i += 256) Ws[i] = W[i];
    __syncthreads();
    int base = blockIdx.x * (4 * RLOOP);
    for (int r = 0; r < RLOOP; ++r) {
        int row = base + r * 4 + ty;
        if (row < n) {
            float v = in[(long long)row * FIN + lane];
            if (RELU_IN) v = fmaxf(v, 0.0f);
            rowbuf[ty][lane] = v;  // wave-private region; lgkmcnt orders it
            float acc = 0.0f;
#pragma unroll
            for (int k = 0; k < FIN; ++k)
                acc = fmaf(rowbuf[ty][k], Ws[k * FOUT + lane], acc);
            if (lane < FOUT) out[(long long)row * FOUT + lane] = acc;
        }
    }
}

// ---------------- gather-aggregate: wave per node, quarter = edge slot -------
// lane = q*16 + f4 ; quarter q handles edges j = 16*g + 4*t + q via float4
// out[i] = h[i]*dinv[i]^2 + b + sum_{e: dst=i} h[src_e] * wgt_e
template <int F>  // F % 4 == 0
__global__ void gather_kernel(const int* __restrict__ rowptr, const int* __restrict__ deg,
                              const int* __restrict__ adj, const float* __restrict__ wgt,
                              const float* __restrict__ h, const float* __restrict__ dinv,
                              const float* __restrict__ b, float* __restrict__ out, int n) {
    int node = blockIdx.x * 4 + (threadIdx.x >> 6);
    int lane = threadIdx.x & 63;
    if (node >= n) return;
    int q = lane >> 4;
    int f4 = lane & 15;
    const bool fval = (f4 < F / 4);
    const float4* h4 = (const float4*)h;
    float4 acc = make_float4(0.f, 0.f, 0.f, 0.f);
    if (q == 0 && fval) {
        float di = dinv[node];
        float4 hv = h4[(long long)node * (F / 4) + f4];
        float4 bv = ((const float4*)b)[f4];
        acc.x = hv.x * di * di + bv.x;
        acc.y = hv.y * di * di + bv.y;
        acc.z = hv.z * di * di + bv.z;
        acc.w = hv.w * di * di + bv.w;
    }
    int r0 = rowptr[node];
    int cnt = deg[node];
    for (int j0 = 0; j0 < cnt; j0 += 64) {
        int m = min(64, cnt - j0);
        int s = 0;          // lane >= m keeps s=0 (safe row), w=0 (no effect)
        float w = 0.0f;
        if (lane < m) {
            s = adj[r0 + j0 + lane];
            w = wgt[r0 + j0 + lane];
        }
#pragma unroll
        for (int g = 0; g < 4; ++g) {
            if (16 * g < m) {   // wave-uniform group guard
#pragma unroll
                for (int t = 0; t < 4; ++t) {
                    int j = 16 * g + 4 * t + q;
                    int st = __shfl(s, j, 64);
                    float wt = __shfl(w, j, 64);
                    if (fval) {
                        float4 hv = h4[(long long)st * (F / 4) + f4];
                        acc.x = fmaf(hv.x, wt, acc.x);
                        acc.y = fmaf(hv.y, wt, acc.y);
                        acc.z = fmaf(hv.z, wt, acc.z);
                        acc.w = fmaf(hv.w, wt, acc.w);
                    }
                }
            }
        }
    }
    // combine the 4 quarters (bit4 and bit5 of lane)
    acc.x += __shfl_xor(acc.x, 16, 64);
    acc.y += __shfl_xor(acc.y, 16, 64);
    acc.z += __shfl_xor(acc.z, 16, 64);
    acc.w += __shfl_xor(acc.w, 16, 64);
    acc.x += __shfl_xor(acc.x, 32, 64);
    acc.y += __shfl_xor(acc.y, 32, 64);
    acc.z += __shfl_xor(acc.z, 32, 64);
    acc.w += __shfl_xor(acc.w, 32, 64);
    if (q == 0 && fval) ((float4*)out)[(long long)node * (F / 4) + f4] = acc;
}

// ---------------- log_softmax over C cols, one wave per row ------------------
template <int C>
__global__ void logsoftmax_kernel(float* __restrict__ out, int n) {
    int wave = threadIdx.x >> 6;
    int lane = threadIdx.x & 63;
    int row = blockIdx.x * 4 + wave;
    if (row >= n) return;
    float v = (lane < C) ? out[(long long)row * C + lane] : -INFINITY;
    float m = v;
#pragma unroll
    for (int off = 32; off >= 1; off >>= 1) m = fmaxf(m, __shfl_xor(m, off, 64));
    float e = (lane < C) ? expf(v - m) : 0.0f;
    float s = e;
#pragma unroll
    for (int off = 32; off >= 1; off >>= 1) s += __shfl_xor(s, off, 64);
    if (lane < C) out[(long long)row * C + lane] = v - m - logf(s);
}

extern "C" void kernel_launch(void* const* d_in, const int* in_sizes, int n_in,
                              void* d_out, int out_size, void* d_ws, size_t ws_size,
                              hipStream_t stream) {
    const float* x  = (const float*)d_in[0];
    const int*   ei = (const int*)d_in[1];
    const float* W0 = (const float*)d_in[2];
    const float* b0 = (const float*)d_in[3];
    const float* W1 = (const float*)d_in[4];
    const float* b1 = (const float*)d_in[5];
    const float* W2 = (const float*)d_in[6];
    const float* b2 = (const float*)d_in[7];
    float* out = (float*)d_out;

    const int H   = in_sizes[3];            // 64
    const int FIN = in_sizes[2] / H;        // 64
    const int n   = in_sizes[0] / FIN;      // 50000
    const int E   = in_sizes[1] / 2;        // 800000
    (void)FIN;

    const int* srcp = ei;
    const int* dstp = ei + E;

    char* ws = (char*)d_ws;
    size_t off = 0;
    int*   deg    = (int*)(ws + off);   off += ws_align((size_t)n * 4);
    int*   cursor = (int*)(ws + off);   off += ws_align((size_t)n * 4);
    int*   rowptr = (int*)(ws + off);   off += ws_align((size_t)n * 4);
    int*   bsum   = (int*)(ws + off);   off += ws_align(256 * 4);
    float* dinv   = (float*)(ws + off); off += ws_align((size_t)n * 4);
    int*   adj    = (int*)(ws + off);   off += ws_align((size_t)E * 4);
    float* wgt    = (float*)(ws + off); off += ws_align((size_t)E * 4);
    float* buf0   = (float*)(ws + off); off += ws_align((size_t)n * H * 4);
    float* buf1   = (float*)(ws + off); off += ws_align((size_t)n * H * 4);

    // zero deg + cursor (adjacent -> single memset covers both)
    hipMemsetAsync(deg, 0, ws_align((size_t)n * 4) * 2, stream);

    // CSR build
    deg_kernel<<<(E + 255) / 256, 256, 0, stream>>>(dstp, E, deg);
    dinv_kernel<<<(n + 255) / 256, 256, 0, stream>>>(deg, dinv, n);
    int nscan = (n + 1023) / 1024;  // 49
    scan1_kernel<<<nscan, 256, 0, stream>>>(deg, bsum, n);
    scan2_kernel<<<1, 256, 0, stream>>>(bsum, nscan);
    scan3_kernel<<<nscan, 256, 0, stream>>>(deg, bsum, rowptr, n);
    fill_kernel<<<(E + 255) / 256, 256, 0, stream>>>(srcp, dstp, dinv, rowptr, cursor, adj, wgt, E);

    const int RLOOP = 8;  // 32 rows per block
    int gemm_grid = (n + 4 * RLOOP - 1) / (4 * RLOOP);
    int node_grid = (n + 3) / 4;

    // layer 0
    gemm_kernel<64, 64, false, RLOOP><<<gemm_grid, 256, 0, stream>>>(x, W0, buf0, n);
    gather_kernel<64><<<node_grid, 256, 0, stream>>>(rowptr, deg, adj, wgt, buf0, dinv, b0, buf1, n);
    // layer 1
    gemm_kernel<64, 64, true, RLOOP><<<gemm_grid, 256, 0, stream>>>(buf1, W1, buf0, n);
    gather_kernel<64><<<node_grid, 256, 0, stream>>>(rowptr, deg, adj, wgt, buf0, dinv, b1, buf1, n);
    // layer 2
    gemm_kernel<64, 40, true, RLOOP><<<gemm_grid, 256, 0, stream>>>(buf1, W2, buf0, n);
    gather_kernel<40><<<node_grid, 256, 0, stream>>>(rowptr, deg, adj, wgt, buf0, dinv, b2, out, n);
    logsoftmax_kernel<40><<<(n + 3) / 4, 256, 0, stream>>>(out, n);
}